// Round 1
// baseline (871.103 us; speedup 1.0000x reference)
//
#include <hip/hip_runtime.h>

// Problem: B=32, T=1024, D=2048 fp32 scan along T.
// out[b,0,:] = x[b,0,:]
// for t>=1:  a = carry[j], bl = carry[j-1] (bl undefined at j==0)
//   j==0 : new = x[b,t,0] + carry[0]
//   j>=1 : p = sigmoid(a-bl); new = x[b,t,j] + bl + p*(a-bl)
// carry <- new; out[b,t,:] = new
//
// Parallelization: grid (NC=8 chunks, B=32), block = 1 wave (64 threads),
// 4 columns/thread (float4). Temporal chain only; cross-chunk boundary value
// handed off through d_ws slots: packed (t<<32)|float_bits, agent-scope
// relaxed atomics. Tag-match spin => no workspace init needed (poison
// 0xAAAAAAAA never matches a step tag in [1,1022]).

#define NC   8
#define BLK  64
#define VPT  4
#define TT   1024
#define DD   2048
#define DPX  16   // x prefetch depth (float4s per thread in flight)
#define DPB  8    // boundary slot prefetch depth

__device__ __forceinline__ float softstep(float a, float bl) {
    // p = sigmoid(a-bl); return bl + p*(a-bl)
    float d = a - bl;
    float p = __builtin_amdgcn_rcpf(1.0f + __expf(-d));
    return fmaf(p, d, bl);
}

__global__ __launch_bounds__(BLK)
void softscan_kernel(const float* __restrict__ x, float* __restrict__ out,
                     unsigned long long* __restrict__ slots) {
    const int k    = blockIdx.x;           // column chunk 0..NC-1
    const int b    = blockIdx.y;           // batch
    const int lane = threadIdx.x;          // 0..63
    const int c0   = k * (BLK * VPT) + lane * VPT;
    const int strideV = DD / 4;            // float4s per row

    const float4* xp = (const float4*)(x + (size_t)b * TT * DD + c0);
    float4*       op = (float4*)(out + (size_t)b * TT * DD + c0);

    // slot layout: [b][kk][tau], kk = publishing chunk 0..NC-2, tau = step
    unsigned long long* pubSlot =
        slots + ((size_t)b * (NC - 1) + k) * TT;          // valid if k < NC-1
    const unsigned long long* rdSlot =
        slots + ((size_t)b * (NC - 1) + (k - 1)) * TT;    // valid if k > 0

    // ---- t = 0 ----
    float4 carry = xp[0];
    op[0] = carry;

    float xleft0 = 0.0f;
    if (k > 0 && lane == 0) xleft0 = x[(size_t)b * TT * DD + (c0 - 1)];

    // ---- prefetch prologue ----
    float4 xbuf[DPX];
    unsigned long long bbuf[DPB];
#pragma unroll
    for (int s = 0; s < DPX; ++s)
        xbuf[s] = xp[(size_t)(s + 1) * strideV];
    if (k > 0 && lane == 0) {
#pragma unroll
        for (int s = 1; s < DPB; ++s)
            bbuf[s] = __hip_atomic_load(&rdSlot[s], __ATOMIC_RELAXED,
                                        __HIP_MEMORY_SCOPE_AGENT);
    }

    // ---- main scan: steps s = 0..1022 (t = s+1) ----
    for (int m = 0; m < 64; ++m) {
#pragma unroll
        for (int j = 0; j < 16; ++j) {
            const int s = m * 16 + j;
            if (s < TT - 1) {
                const int t = s + 1;
                float4 xv = xbuf[j];          // (s & 15) == j

                // left-boundary value for lane 0 (column c0-1 at step s)
                float leftv = 0.0f;
                if (k > 0 && lane == 0) {
                    if (s == 0) {
                        leftv = xleft0;
                    } else {
                        unsigned long long raw = bbuf[j & 7];
                        while ((unsigned)(raw >> 32) != (unsigned)s)
                            raw = __hip_atomic_load(&rdSlot[s], __ATOMIC_RELAXED,
                                                    __HIP_MEMORY_SCOPE_AGENT);
                        leftv = __uint_as_float((unsigned)raw);
                    }
                }
                float sh   = __shfl_up(carry.w, 1);
                float left = (lane == 0) ? leftv : sh;

                float n0;
                if (k == 0 && lane == 0) n0 = xv.x + carry.x;      // global col 0
                else                     n0 = xv.x + softstep(carry.x, left);
                float n1 = xv.y + softstep(carry.y, carry.x);
                float n2 = xv.z + softstep(carry.z, carry.y);
                float n3 = xv.w + softstep(carry.w, carry.z);
                carry = make_float4(n0, n1, n2, n3);

                op[(size_t)t * strideV] = carry;

                // publish last column of this chunk for right neighbor
                if (k < NC - 1 && lane == BLK - 1 && t <= TT - 2) {
                    unsigned long long pk =
                        ((unsigned long long)(unsigned)t << 32) |
                        (unsigned long long)__float_as_uint(carry.w);
                    __hip_atomic_store(&pubSlot[t], pk, __ATOMIC_RELAXED,
                                       __HIP_MEMORY_SCOPE_AGENT);
                }

                // prefetch x row s+17 into xbuf[j]
                const int spx = s + DPX;
                if (spx <= TT - 2)
                    xbuf[j] = xp[(size_t)(spx + 1) * strideV];
                // prefetch boundary slot s+8 into bbuf[j&7]
                const int spb = s + DPB;
                if (k > 0 && lane == 0 && spb <= TT - 2)
                    bbuf[j & 7] = __hip_atomic_load(&rdSlot[spb], __ATOMIC_RELAXED,
                                                    __HIP_MEMORY_SCOPE_AGENT);
            }
        }
    }
}

extern "C" void kernel_launch(void* const* d_in, const int* in_sizes, int n_in,
                              void* d_out, int out_size, void* d_ws, size_t ws_size,
                              hipStream_t stream) {
    const float* x = (const float*)d_in[0];
    float* out = (float*)d_out;
    unsigned long long* slots = (unsigned long long*)d_ws;
    // ws usage: 32 * (NC-1) * 1024 * 8 bytes = 1.75 MB (tag-match => no init)
    dim3 grid(NC, 32);
    dim3 block(BLK);
    softscan_kernel<<<grid, block, 0, stream>>>(x, out, slots);
}

// Round 2
// 685.128 us; speedup vs baseline: 1.2714x; 1.2714x over previous
//
#include <hip/hip_runtime.h>

// B=32, T=1024, D=2048 fp32 scan along T.
// out[b,0,:] = x[b,0,:]
// t>=1: a=carry[j], bl=carry[j-1]; j==0: new = x+carry[0];
//       j>=1: p=sigmoid(a-bl); new = x + bl + p*(a-bl)
//
// Grid (32 batches, NC chunks), block = 1 wave. VPT cols/thread (vector).
// Temporal chain only; cross-chunk boundary via packed (t<<32|bits) slots in
// d_ws, agent-scope relaxed atomics, tag-match spin (0xAA poison never
// matches tags 1..1022 => no ws init). Grid ordered so all chunks of a batch
// land on one XCD (linear id = b + 32k => XCD b%8).
// __launch_bounds__(64,1): allow up to 512 VGPRs so the DPX-deep prefetch
// pipeline stays in registers (R1 had VGPR_Count=64 => pipeline collapsed,
// 1340 cyc/step, 9% HBM).

#define TT  1024
#define DD  2048
#define BLK 64
#define DPX 16   // x prefetch depth (vec loads in flight per thread)
#define DPB 8    // boundary slot prefetch depth

__device__ __forceinline__ float softstep(float a, float bl) {
    float d = a - bl;
    float p = __builtin_amdgcn_rcpf(1.0f + __expf(-d));
    return fmaf(p, d, bl);
}

template<int NC>
__global__ __launch_bounds__(BLK, 1)
void softscan_kernel(const float* __restrict__ x, float* __restrict__ out,
                     unsigned long long* __restrict__ slots)
{
    constexpr int VPT = DD / NC / BLK;
    typedef float vecN __attribute__((ext_vector_type(VPT)));

    const int b    = blockIdx.x;           // batch (XCD = b%8)
    const int k    = blockIdx.y;           // column chunk
    const int lane = threadIdx.x;
    const int c0   = k * (BLK * VPT) + lane * VPT;
    const int strideV = DD / VPT;

    const vecN* __restrict__ xp = (const vecN*)(x + (size_t)b * TT * DD + c0);
    vecN* __restrict__ op       = (vecN*)(out + (size_t)b * TT * DD + c0);

    unsigned long long* pubSlot =
        slots + ((size_t)b * (NC - 1) + k) * TT;          // valid if k < NC-1
    const unsigned long long* rdSlot =
        slots + ((size_t)b * (NC - 1) + (k - 1)) * TT;    // valid if k > 0

    // t = 0
    vecN carry = xp[0];
    __builtin_nontemporal_store(carry, &op[0]);

    float xleft0 = 0.0f;
    if (k > 0 && lane == 0) xleft0 = x[(size_t)b * TT * DD + (c0 - 1)];

    // prefetch prologue
    vecN xbuf[DPX];
    unsigned long long bbuf[DPB];
#pragma unroll
    for (int s = 0; s < DPX; ++s)
        xbuf[s] = xp[(size_t)(s + 1) * strideV];
    if (k > 0 && lane == 0) {
#pragma unroll
        for (int s = 1; s < DPB; ++s)
            bbuf[s] = __hip_atomic_load(&rdSlot[s], __ATOMIC_RELAXED,
                                        __HIP_MEMORY_SCOPE_AGENT);
    }

#define STEP_BODY(S_, J_, PF_X_)                                              \
    {                                                                         \
        const int s = (S_);                                                   \
        const int t = s + 1;                                                  \
        vecN xv = xbuf[(J_)];                                                 \
        float leftv = 0.0f;                                                   \
        if (k > 0 && lane == 0) {                                             \
            if (s == 0) leftv = xleft0;                                       \
            else {                                                            \
                unsigned long long raw = bbuf[(J_) & (DPB - 1)];              \
                while ((unsigned)(raw >> 32) != (unsigned)s)                  \
                    raw = __hip_atomic_load(&rdSlot[s], __ATOMIC_RELAXED,     \
                                            __HIP_MEMORY_SCOPE_AGENT);        \
                leftv = __uint_as_float((unsigned)raw);                       \
            }                                                                 \
        }                                                                     \
        float sh   = __shfl_up(carry[VPT - 1], 1);                            \
        float left = (lane == 0) ? leftv : sh;                                \
        vecN n;                                                               \
        float s0 = softstep(carry[0], left);                                  \
        n[0] = xv[0] + ((k == 0 && lane == 0) ? carry[0] : s0);               \
        _Pragma("unroll")                                                     \
        for (int i = 1; i < VPT; ++i)                                         \
            n[i] = xv[i] + softstep(carry[i], carry[i - 1]);                  \
        carry = n;                                                            \
        __builtin_nontemporal_store(carry, &op[(size_t)t * strideV]);         \
        if (k < NC - 1 && lane == BLK - 1 && t <= TT - 2) {                   \
            unsigned long long pk =                                           \
                ((unsigned long long)(unsigned)t << 32) |                     \
                (unsigned long long)__float_as_uint(carry[VPT - 1]);          \
            __hip_atomic_store(&pubSlot[t], pk, __ATOMIC_RELAXED,             \
                               __HIP_MEMORY_SCOPE_AGENT);                     \
        }                                                                     \
        if (PF_X_) {                                                          \
            int row = s + DPX + 1; if (row > TT - 1) row = TT - 1;            \
            xbuf[(J_)] = xp[(size_t)row * strideV];                           \
        }                                                                     \
        const int spb = s + DPB;                                              \
        if (k > 0 && lane == 0 && spb <= TT - 2)                              \
            bbuf[(J_) & (DPB - 1)] =                                          \
                __hip_atomic_load(&rdSlot[spb], __ATOMIC_RELAXED,             \
                                  __HIP_MEMORY_SCOPE_AGENT);                  \
    }

    // main: 63 * 16 steps, s = 0..1007
    for (int m = 0; m < (TT - 1) / DPX; ++m) {
#pragma unroll
        for (int j = 0; j < DPX; ++j)
            STEP_BODY(m * DPX + j, j, true)
    }
    // epilogue: 15 steps, s = 1008..1022 (buffer index = s % 16 = e)
#pragma unroll
    for (int e = 0; e < (TT - 1) % DPX; ++e)
        STEP_BODY(((TT - 1) / DPX) * DPX + e, e, false)

#undef STEP_BODY
}

extern "C" void kernel_launch(void* const* d_in, const int* in_sizes, int n_in,
                              void* d_out, int out_size, void* d_ws, size_t ws_size,
                              hipStream_t stream) {
    const float* x = (const float*)d_in[0];
    float* out = (float*)d_out;
    unsigned long long* slots = (unsigned long long*)d_ws;
    const size_t need16 = (size_t)32 * 15 * TT * sizeof(unsigned long long); // 3.75 MB
    if (ws_size >= need16) {
        // NC=16: VPT=2, 512 blocks (2/CU), lower reg pressure, intra-XCD handoffs
        softscan_kernel<16><<<dim3(32, 16), dim3(BLK), 0, stream>>>(x, out, slots);
    } else {
        // fallback: NC=8, VPT=4, 1.75 MB ws
        softscan_kernel<8><<<dim3(32, 8), dim3(BLK), 0, stream>>>(x, out, slots);
    }
}